// Round 1
// baseline (2315.790 us; speedup 1.0000x reference)
//
#include <hip/hip_runtime.h>
#include <math.h>

#define HW 16384
#define NB 2
#define NC 192
#define WPAD 196

// ---------------------------------------------------------------------------
// Kernel 1: pointwise GEMM  out[b][pix][o'] = sum_c w[orow(o')][c] * x[b][c][pix]
// o' = head*32+ch permutation baked into weight-row gather.
// block: 64 pixels x 64 o' chunk; 256 thr, each 4px x 4o.
// ---------------------------------------------------------------------------
__device__ inline void fma4_qkv(float4& a, const float4 w0, const float4 w1,
                                const float4 w2, const float4 w3,
                                float x0, float x1, float x2, float x3) {
  a.x += w0.x * x0 + w0.y * x1 + w0.z * x2 + w0.w * x3;
  a.y += w1.x * x0 + w1.y * x1 + w1.z * x2 + w1.w * x3;
  a.z += w2.x * x0 + w2.y * x1 + w2.z * x2 + w2.w * x3;
  a.w += w3.x * x0 + w3.y * x1 + w3.z * x2 + w3.w * x3;
}

__global__ __launch_bounds__(256) void k_gemm_qkv(
    const float* __restrict__ x, const float* __restrict__ w,
    float* __restrict__ outA, float* __restrict__ outB, float scale) {
  __shared__ float xl[NC * 64];
  __shared__ float wl[64 * WPAD];
  const int tid = threadIdx.x;
  const int tile = blockIdx.x;
  const int b = tile >> 8;
  const int p0 = (tile & 255) << 6;
  const float* xb = x + (size_t)b * NC * HW + p0;
  for (int i = tid; i < NC * 64; i += 256) {
    int c = i >> 6, pix = i & 63;
    xl[i] = xb[(size_t)c * HW + pix];
  }
  const int oc0 = blockIdx.y << 6;
  for (int i = tid; i < 64 * NC; i += 256) {
    int o = i / NC, c = i - o * NC;
    int op = oc0 + o;
    int t = op >= NC ? 1 : 0;
    int cc = op - t * NC;
    int orow = t * NC + (cc & 31) * 6 + (cc >> 5);
    wl[o * WPAD + c] = w[(size_t)orow * NC + c];
  }
  __syncthreads();
  const int pg = tid & 15, og = tid >> 4;
  float4 a0 = make_float4(0.f, 0.f, 0.f, 0.f);
  float4 a1 = a0, a2 = a0, a3 = a0;
  const float* wbase = &wl[(og * 4) * WPAD];
  const float* xbase = &xl[pg * 4];
  for (int c = 0; c < NC; c += 4) {
    float4 w0 = *(const float4*)(wbase + c);
    float4 w1 = *(const float4*)(wbase + WPAD + c);
    float4 w2 = *(const float4*)(wbase + 2 * WPAD + c);
    float4 w3 = *(const float4*)(wbase + 3 * WPAD + c);
    float4 x0 = *(const float4*)(xbase + (c + 0) * 64);
    float4 x1 = *(const float4*)(xbase + (c + 1) * 64);
    float4 x2 = *(const float4*)(xbase + (c + 2) * 64);
    float4 x3 = *(const float4*)(xbase + (c + 3) * 64);
    fma4_qkv(a0, w0, w1, w2, w3, x0.x, x1.x, x2.x, x3.x);
    fma4_qkv(a1, w0, w1, w2, w3, x0.y, x1.y, x2.y, x3.y);
    fma4_qkv(a2, w0, w1, w2, w3, x0.z, x1.z, x2.z, x3.z);
    fma4_qkv(a3, w0, w1, w2, w3, x0.w, x1.w, x2.w, x3.w);
  }
  const int t = oc0 >= NC ? 1 : 0;
  float* dst = t ? outB : outA;
  const int od = oc0 - t * NC + og * 4;
  const size_t prow = (size_t)b * HW + p0 + pg * 4;
  float4 accs[4] = {a0, a1, a2, a3};
#pragma unroll
  for (int p = 0; p < 4; ++p) {
    float4 r = accs[p];
    r.x *= scale; r.y *= scale; r.z *= scale; r.w *= scale;
    *(float4*)&dst[(prow + p) * NC + od] = r;
  }
}

// ---------------------------------------------------------------------------
// Kernel 2: fused conv3x3(384->192)+bias+relu -> off head (18ch)
// block: 8x8 spatial tile; 256 thr = 64px x 4 o-groups (48 o each, wave-uniform)
// ---------------------------------------------------------------------------
__global__ __launch_bounds__(256) void k_conv_off(
    const float* __restrict__ xq, const float* __restrict__ xkv,
    const float* __restrict__ w1, const float* __restrict__ b1,
    const float* __restrict__ w2, const float* __restrict__ b2,
    float* __restrict__ off) {
  __shared__ float plds[64 * 4 * 18];
  const int tid = threadIdx.x;
  const int tile = blockIdx.x;
  const int b = tile >> 8;
  const int ty = ((tile >> 4) & 15) << 3;
  const int tx = (tile & 15) << 3;
  const int lpx = tid & 63;
  const int og = __builtin_amdgcn_readfirstlane(tid >> 6);
  const int py = lpx >> 3, px = lpx & 7;
  const int y = ty + py, x = tx + px;
  int offp[9];
  float msk[9];
#pragma unroll
  for (int t = 0; t < 9; ++t) {
    int dy = t / 3 - 1, dx = t % 3 - 1;
    int yy = y + dy, xx = x + dx;
    bool ok = (yy >= 0) && (yy < 128) && (xx >= 0) && (xx < 128);
    msk[t] = ok ? 1.f : 0.f;
    offp[t] = ok ? (yy * 128 + xx) : 0;
  }
  const float* bq = xq + (size_t)b * NC * HW;
  const float* bkv = xkv + (size_t)b * NC * HW;
  float acc[48];
  const float* b1p = b1 + og * 48;
#pragma unroll
  for (int o = 0; o < 48; ++o) acc[o] = b1p[o];
  for (int ic0 = 0; ic0 < 384; ic0 += 8) {
    const float* src =
        (ic0 < NC) ? (bq + (size_t)ic0 * HW) : (bkv + (size_t)(ic0 - NC) * HW);
    float xv[72];
#pragma unroll
    for (int i = 0; i < 8; ++i)
#pragma unroll
      for (int t = 0; t < 9; ++t)
        xv[i * 9 + t] = src[(size_t)i * HW + offp[t]] * msk[t];
    const float* wrow = w1 + (size_t)(og * 48) * 3456 + ic0 * 9;
    for (int o = 0; o < 48; ++o) {
      const float* wp = wrow + (size_t)o * 3456;
      float s = acc[o];
#pragma unroll
      for (int kk = 0; kk < 72; ++kk) s += wp[kk] * xv[kk];
      acc[o] = s;
    }
  }
#pragma unroll
  for (int o = 0; o < 48; ++o) acc[o] = fmaxf(acc[o], 0.f);
  float part[18];
#pragma unroll
  for (int j = 0; j < 18; ++j) part[j] = 0.f;
  for (int j = 0; j < 18; ++j) {
    const float* w2p = w2 + (size_t)j * NC + og * 48;
    float s = 0.f;
#pragma unroll
    for (int o = 0; o < 48; ++o) s += w2p[o] * acc[o];
    part[j] = s;
  }
#pragma unroll
  for (int j = 0; j < 18; ++j) plds[(lpx * 4 + og) * 18 + j] = part[j];
  __syncthreads();
  for (int i = tid; i < 64 * 18; i += 256) {
    int pxi = i / 18, j = i - pxi * 18;
    float s = b2[j] + plds[(pxi * 4 + 0) * 18 + j] + plds[(pxi * 4 + 1) * 18 + j] +
              plds[(pxi * 4 + 2) * 18 + j] + plds[(pxi * 4 + 3) * 18 + j];
    int yy = ty + (pxi >> 3), xx = tx + (pxi & 7);
    off[((size_t)b * HW + yy * 128 + xx) * 18 + j] = s;
  }
}

// ---------------------------------------------------------------------------
// Kernel 3: deformable sampling + 3x3-window attention. One wave per pixel.
// lane -> channels o' = lane, lane+64, lane+128; head = (lane>>5)+2j.
// ---------------------------------------------------------------------------
__global__ __launch_bounds__(256) void k_attn(
    const float* __restrict__ q, const float* __restrict__ k,
    const float* __restrict__ v, const float* __restrict__ off,
    float* __restrict__ pre) {
  __shared__ float slog[4][6][9];
  __shared__ float sattn[4][6][9];
  const int wv = threadIdx.x >> 6;
  const int lane = threadIdx.x & 63;
  const size_t p = (size_t)blockIdx.x * 4 + wv;
  const int b = (int)(p >> 14);
  const int pp = (int)(p & 16383);
  const int y = pp >> 7, x = pp & 127;
  const float* qrow = q + p * NC;
  float qv0 = qrow[lane], qv1 = qrow[lane + 64], qv2 = qrow[lane + 128];
  float vsr[9][3];
#pragma unroll
  for (int idx = 0; idx < 9; ++idx) {
    const int di = idx / 3 - 1, dj = idx % 3 - 1;
    const int yy = y + di, xx = x + dj;
    const bool inb = (yy >= 0) && (yy < 128) && (xx >= 0) && (xx < 128);
    float ks0 = 0.f, ks1 = 0.f, ks2 = 0.f;
    float v0 = 0.f, v1 = 0.f, v2 = 0.f;
    if (inb) {
      const size_t sp = (size_t)b * HW + yy * 128 + xx;
      const float sx = off[sp * 18 + idx * 2 + 0];
      const float sy = off[sp * 18 + idx * 2 + 1];
      const float fx0 = floorf(sx), fy0 = floorf(sy);
      const float wx = sx - fx0, wy = sy - fy0;
#pragma unroll
      for (int cyx = 0; cyx < 4; ++cyx) {
        const int cy = cyx >> 1, cx = cyx & 1;
        const float xi = fx0 + cx, yi = fy0 + cy;
        const float wgt = (cx ? wx : 1.f - wx) * (cy ? wy : 1.f - wy);
        const bool okc = (xi >= 0.f) && (xi <= 127.f) && (yi >= 0.f) && (yi <= 127.f);
        if (okc) {
          const int xc = (int)xi, yc = (int)yi;
          const size_t cb = ((size_t)b * HW + yc * 128 + xc) * NC + lane;
          ks0 += wgt * k[cb];       v0 += wgt * v[cb];
          ks1 += wgt * k[cb + 64];  v1 += wgt * v[cb + 64];
          ks2 += wgt * k[cb + 128]; v2 += wgt * v[cb + 128];
        }
      }
    }
    vsr[idx][0] = v0; vsr[idx][1] = v1; vsr[idx][2] = v2;
    float p0 = qv0 * ks0, p1 = qv1 * ks1, p2 = qv2 * ks2;
#pragma unroll
    for (int m = 16; m >= 1; m >>= 1) {
      p0 += __shfl_xor(p0, m);
      p1 += __shfl_xor(p1, m);
      p2 += __shfl_xor(p2, m);
    }
    if ((lane & 31) == 0) {
      const int hb = lane >> 5;
      slog[wv][hb + 0][idx] = p0;
      slog[wv][hb + 2][idx] = p1;
      slog[wv][hb + 4][idx] = p2;
    }
  }
  __syncthreads();
  if (lane < 6) {
    float mx = -1e30f;
#pragma unroll
    for (int i = 0; i < 9; ++i) mx = fmaxf(mx, slog[wv][lane][i]);
    float e[9];
    float s = 0.f;
#pragma unroll
    for (int i = 0; i < 9; ++i) { e[i] = expf(slog[wv][lane][i] - mx); s += e[i]; }
    const float inv = 1.f / s;
#pragma unroll
    for (int i = 0; i < 9; ++i) sattn[wv][lane][i] = e[i] * inv;
  }
  __syncthreads();
  float o0 = 0.f, o1 = 0.f, o2 = 0.f;
  const int hb = lane >> 5;
#pragma unroll
  for (int idx = 0; idx < 9; ++idx) {
    o0 += sattn[wv][hb + 0][idx] * vsr[idx][0];
    o1 += sattn[wv][hb + 2][idx] * vsr[idx][1];
    o2 += sattn[wv][hb + 4][idx] * vsr[idx][2];
  }
  float* prow = pre + p * NC;
  prow[lane] = o0;
  prow[lane + 64] = o1;
  prow[lane + 128] = o2;
}

// ---------------------------------------------------------------------------
// Kernel 4: proj  out[b][oc][pix] = b_proj[oc] + sum_{o'} w_proj[oc][perm(o')]*pre[pix][o']
// ---------------------------------------------------------------------------
__device__ inline void fma4_proj(float4& a, const float4 w, const float4 x0,
                                 const float4 x1, const float4 x2, const float4 x3) {
  a.x += w.x * x0.x + w.y * x1.x + w.z * x2.x + w.w * x3.x;
  a.y += w.x * x0.y + w.y * x1.y + w.z * x2.y + w.w * x3.y;
  a.z += w.x * x0.z + w.y * x1.z + w.z * x2.z + w.w * x3.z;
  a.w += w.x * x0.w + w.y * x1.w + w.z * x2.w + w.w * x3.w;
}

__global__ __launch_bounds__(256) void k_proj(
    const float* __restrict__ pre, const float* __restrict__ wp,
    const float* __restrict__ bp, float* __restrict__ out) {
  __shared__ float xl[NC * 68];
  __shared__ float wl[64 * WPAD];
  const int tid = threadIdx.x;
  const int tile = blockIdx.x;
  const int b = tile >> 8;
  const int p0 = (tile & 255) << 6;
  const float* pb = pre + ((size_t)b * HW + p0) * NC;
  for (int i = tid; i < 64 * NC; i += 256) {
    int pix = i / NC, c = i - pix * NC;
    xl[c * 68 + pix] = pb[i];
  }
  const int oc0 = blockIdx.y << 6;
  for (int i = tid; i < 64 * NC; i += 256) {
    int o = i / NC, c = i - o * NC;
    wl[o * WPAD + c] = wp[(size_t)(oc0 + o) * NC + ((c & 31) * 6 + (c >> 5))];
  }
  __syncthreads();
  const int pg = tid & 15, og = tid >> 4;
  float bi0 = bp[oc0 + og * 4 + 0];
  float bi1 = bp[oc0 + og * 4 + 1];
  float bi2 = bp[oc0 + og * 4 + 2];
  float bi3 = bp[oc0 + og * 4 + 3];
  float4 a0 = make_float4(bi0, bi0, bi0, bi0);
  float4 a1 = make_float4(bi1, bi1, bi1, bi1);
  float4 a2 = make_float4(bi2, bi2, bi2, bi2);
  float4 a3 = make_float4(bi3, bi3, bi3, bi3);
  const float* wbase = &wl[(og * 4) * WPAD];
  const float* xbase = &xl[pg * 4];
  for (int c = 0; c < NC; c += 4) {
    float4 w0 = *(const float4*)(wbase + c);
    float4 w1 = *(const float4*)(wbase + WPAD + c);
    float4 w2 = *(const float4*)(wbase + 2 * WPAD + c);
    float4 w3 = *(const float4*)(wbase + 3 * WPAD + c);
    float4 x0 = *(const float4*)(xbase + (c + 0) * 68);
    float4 x1 = *(const float4*)(xbase + (c + 1) * 68);
    float4 x2 = *(const float4*)(xbase + (c + 2) * 68);
    float4 x3 = *(const float4*)(xbase + (c + 3) * 68);
    fma4_proj(a0, w0, x0, x1, x2, x3);
    fma4_proj(a1, w1, x0, x1, x2, x3);
    fma4_proj(a2, w2, x0, x1, x2, x3);
    fma4_proj(a3, w3, x0, x1, x2, x3);
  }
  float* ob = out + ((size_t)b * NC + oc0 + og * 4) * HW + p0 + pg * 4;
  *(float4*)(ob + 0 * (size_t)HW) = a0;
  *(float4*)(ob + 1 * (size_t)HW) = a1;
  *(float4*)(ob + 2 * (size_t)HW) = a2;
  *(float4*)(ob + 3 * (size_t)HW) = a3;
}

extern "C" void kernel_launch(void* const* d_in, const int* in_sizes, int n_in,
                              void* d_out, int out_size, void* d_ws, size_t ws_size,
                              hipStream_t stream) {
  const float* x_q    = (const float*)d_in[0];
  const float* x_kv   = (const float*)d_in[1];
  const float* w_q    = (const float*)d_in[2];
  const float* w_kv   = (const float*)d_in[3];
  const float* w_off1 = (const float*)d_in[4];
  const float* b_off1 = (const float*)d_in[5];
  const float* w_off2 = (const float*)d_in[6];
  const float* b_off2 = (const float*)d_in[7];
  const float* w_proj = (const float*)d_in[8];
  const float* b_proj = (const float*)d_in[9];
  float* out = (float*)d_out;
  float* ws = (float*)d_ws;

  const size_t NPB = (size_t)NB * HW * NC;  // 6291456 floats per field
  float* qb   = ws;
  float* kb   = ws + NPB;
  float* vb   = ws + 2 * NPB;
  float* preb = ws + 3 * NPB;
  float* offb = ws + 4 * NPB;  // NB*HW*18 floats

  const float scale = 0.17677669529663687f;  // 32^-0.5
  dim3 blk(256);
  k_gemm_qkv<<<dim3(512, 3), blk, 0, stream>>>(x_q, w_q, qb, qb, scale);
  k_gemm_qkv<<<dim3(512, 6), blk, 0, stream>>>(x_kv, w_kv, kb, vb, 1.0f);
  k_conv_off<<<dim3(512), blk, 0, stream>>>(x_q, x_kv, w_off1, b_off1, w_off2,
                                            b_off2, offb);
  k_attn<<<dim3(8192), blk, 0, stream>>>(qb, kb, vb, offb, preb);
  k_proj<<<dim3(512, 3), blk, 0, stream>>>(preb, w_proj, b_proj, out);
}

// Round 2
// 542.001 us; speedup vs baseline: 4.2727x; 4.2727x over previous
//
#include <hip/hip_runtime.h>
#include <math.h>

#define HW 16384
#define NB 2
#define NC 192
#define WPAD 196

typedef __attribute__((ext_vector_type(8))) short bh8;
typedef __attribute__((ext_vector_type(4))) float f32x4;

__device__ inline ushort f2bf(float f) {
  union { float f; unsigned int u; } x; x.f = f;
  unsigned int r = x.u + 0x7fffu + ((x.u >> 16) & 1u);
  return (ushort)(r >> 16);
}

// ---------------------------------------------------------------------------
// Kernel 0: pack conv weights -> wpack[s=108][o=192][kk=32] bf16
// s = (dy*12+icc)*3+dxi, ic = icc*32+kk. Stored in d_out (dead until k_proj).
// ---------------------------------------------------------------------------
__global__ void k_wpack(const float* __restrict__ w1, ushort* __restrict__ wpack) {
  int i = blockIdx.x * 256 + threadIdx.x;  // 663552 total
  int s = i / 6144;
  int rem = i - s * 6144;
  int o = rem >> 5, kk = rem & 31;
  int dy = s / 36, t2 = s - dy * 36;
  int icc = t2 / 3, dxi = t2 - icc * 3;
  int ic = icc * 32 + kk;
  float v = w1[(size_t)o * 3456 + (size_t)ic * 9 + dy * 3 + dxi];
  wpack[i] = f2bf(v);
}

// ---------------------------------------------------------------------------
// Kernel 1: pointwise GEMM (q / kv), unchanged from R1.
// ---------------------------------------------------------------------------
__device__ inline void fma4_qkv(float4& a, const float4 w0, const float4 w1,
                                const float4 w2, const float4 w3,
                                float x0, float x1, float x2, float x3) {
  a.x += w0.x * x0 + w0.y * x1 + w0.z * x2 + w0.w * x3;
  a.y += w1.x * x0 + w1.y * x1 + w1.z * x2 + w1.w * x3;
  a.z += w2.x * x0 + w2.y * x1 + w2.z * x2 + w2.w * x3;
  a.w += w3.x * x0 + w3.y * x1 + w3.z * x2 + w3.w * x3;
}

__global__ __launch_bounds__(256) void k_gemm_qkv(
    const float* __restrict__ x, const float* __restrict__ w,
    float* __restrict__ outA, float* __restrict__ outB, float scale) {
  __shared__ float xl[NC * 64];
  __shared__ float wl[64 * WPAD];
  const int tid = threadIdx.x;
  const int tile = blockIdx.x;
  const int b = tile >> 8;
  const int p0 = (tile & 255) << 6;
  const float* xb = x + (size_t)b * NC * HW + p0;
  for (int i = tid; i < NC * 64; i += 256) {
    int c = i >> 6, pix = i & 63;
    xl[i] = xb[(size_t)c * HW + pix];
  }
  const int oc0 = blockIdx.y << 6;
  for (int i = tid; i < 64 * NC; i += 256) {
    int o = i / NC, c = i - o * NC;
    int op = oc0 + o;
    int t = op >= NC ? 1 : 0;
    int cc = op - t * NC;
    int orow = t * NC + (cc & 31) * 6 + (cc >> 5);
    wl[o * WPAD + c] = w[(size_t)orow * NC + c];
  }
  __syncthreads();
  const int pg = tid & 15, og = tid >> 4;
  float4 a0 = make_float4(0.f, 0.f, 0.f, 0.f);
  float4 a1 = a0, a2 = a0, a3 = a0;
  const float* wbase = &wl[(og * 4) * WPAD];
  const float* xbase = &xl[pg * 4];
  for (int c = 0; c < NC; c += 4) {
    float4 w0 = *(const float4*)(wbase + c);
    float4 w1 = *(const float4*)(wbase + WPAD + c);
    float4 w2 = *(const float4*)(wbase + 2 * WPAD + c);
    float4 w3 = *(const float4*)(wbase + 3 * WPAD + c);
    float4 x0 = *(const float4*)(xbase + (c + 0) * 64);
    float4 x1 = *(const float4*)(xbase + (c + 1) * 64);
    float4 x2 = *(const float4*)(xbase + (c + 2) * 64);
    float4 x3 = *(const float4*)(xbase + (c + 3) * 64);
    fma4_qkv(a0, w0, w1, w2, w3, x0.x, x1.x, x2.x, x3.x);
    fma4_qkv(a1, w0, w1, w2, w3, x0.y, x1.y, x2.y, x3.y);
    fma4_qkv(a2, w0, w1, w2, w3, x0.z, x1.z, x2.z, x3.z);
    fma4_qkv(a3, w0, w1, w2, w3, x0.w, x1.w, x2.w, x3.w);
  }
  const int t = oc0 >= NC ? 1 : 0;
  float* dst = t ? outB : outA;
  const int od = oc0 - t * NC + og * 4;
  const size_t prow = (size_t)b * HW + p0 + pg * 4;
  float4 accs[4] = {a0, a1, a2, a3};
#pragma unroll
  for (int p = 0; p < 4; ++p) {
    float4 r = accs[p];
    r.x *= scale; r.y *= scale; r.z *= scale; r.w *= scale;
    *(float4*)&dst[(prow + p) * NC + od] = r;
  }
}

// ---------------------------------------------------------------------------
// Kernel 2: conv3x3(384->192) via bf16 MFMA implicit im2col.
// Block: 64 px (one half-row), 4 waves; wave owns 48 out-ch x 64 px.
// K order: (dy, icc, dx); P[72 slots][32 ic] staged once per (dy,icc).
// LDS rows 64B dense, XOR-swizzled 16B chunks (conflict-free b128).
// Output h1[o][p] fp32 (+bias, relu).
// ---------------------------------------------------------------------------
__global__ __launch_bounds__(256, 2) void k_conv_mfma(
    const float* __restrict__ xq, const float* __restrict__ xkv,
    const ushort* __restrict__ wpack, const float* __restrict__ b1,
    float* __restrict__ h1) {
  __shared__ __attribute__((aligned(16))) char smem[41472];  // 3*12288 W + 4608 P
  const int tid = threadIdx.x;
  const int bi = blockIdx.x;
  const int b = bi >> 8;
  const int y = (bi >> 1) & 127;
  const int x0 = (bi & 1) << 6;
  const int lid = tid & 15;
  const int g = (tid >> 4) & 3;
  const int wv = tid >> 6;
  f32x4 acc[3][4];
#pragma unroll
  for (int m = 0; m < 3; ++m)
#pragma unroll
    for (int n = 0; n < 4; ++n) acc[m][n] = (f32x4){0.f, 0.f, 0.f, 0.f};
  const size_t xb = (size_t)b * NC * HW;

  for (int dy = 0; dy < 3; ++dy) {
    const int yy = y + dy - 1;
    const bool yok = (yy >= 0) && (yy < 128);
    for (int icc = 0; icc < 12; ++icc) {
      __syncthreads();
      // ---- stage P: 18 groups of 4 px x 32 ic = 576 tasks
#pragma unroll
      for (int it = 0; it < 3; ++it) {
        int i = tid + (it << 8);
        if (i < 576) {
          int g4 = i >> 5, kk = i & 31;
          int xg = x0 - 4 + (g4 << 2);
          int c = icc * 32 + kk;
          float4 v = make_float4(0.f, 0.f, 0.f, 0.f);
          if (yok && xg >= 0 && xg <= 124) {
            const float* src = (c < NC) ? (xq + xb + (size_t)c * HW)
                                        : (xkv + xb + (size_t)(c - NC) * HW);
            v = *(const float4*)(src + yy * 128 + xg);
          }
          ushort bfv[4] = {f2bf(v.x), f2bf(v.y), f2bf(v.z), f2bf(v.w)};
          int q = kk >> 3, klo = (kk & 7) << 1;
#pragma unroll
          for (int e = 0; e < 4; ++e) {
            int slot = (g4 << 2) + e;
            *(ushort*)(smem + 36864 + slot * 64 +
                       (((q ^ (slot >> 1)) & 3) << 4) + klo) = bfv[e];
          }
        }
      }
      // ---- stage W: 3 dx chunks x 192 o x 4 16B-chunks = 2304 tasks
      const int s0 = (dy * 12 + icc) * 3;
#pragma unroll
      for (int it = 0; it < 9; ++it) {
        int i = tid + (it << 8);
        int dxi = i / 768;
        int rem = i - dxi * 768;
        int o = rem >> 2, q = rem & 3;
        uint4 wq = *(const uint4*)(wpack + (size_t)(s0 + dxi) * 6144 + rem * 8);
        *(uint4*)(smem + dxi * 12288 + o * 64 + (((q ^ (o >> 1)) & 3) << 4)) = wq;
      }
      __syncthreads();
      // ---- compute: 3 dx steps x (3m x 4n) MFMA
#pragma unroll
      for (int dxi = 0; dxi < 3; ++dxi) {
        bh8 af[3], bfr[4];
#pragma unroll
        for (int m = 0; m < 3; ++m) {
          int o = wv * 48 + m * 16 + lid;
          af[m] = *(const bh8*)(smem + dxi * 12288 + o * 64 +
                                (((g ^ (o >> 1)) & 3) << 4));
        }
#pragma unroll
        for (int n = 0; n < 4; ++n) {
          int slot = n * 16 + lid + 3 + dxi;
          bfr[n] = *(const bh8*)(smem + 36864 + slot * 64 +
                                 (((g ^ (slot >> 1)) & 3) << 4));
        }
#pragma unroll
        for (int m = 0; m < 3; ++m)
#pragma unroll
          for (int n = 0; n < 4; ++n)
            acc[m][n] = __builtin_amdgcn_mfma_f32_16x16x32_bf16(
                af[m], bfr[n], acc[m][n], 0, 0, 0);
      }
    }
  }
  // ---- epilogue: h1[o][p] = relu(acc + b1)
  const size_t pbase = (size_t)b * HW + y * 128 + x0;
#pragma unroll
  for (int m = 0; m < 3; ++m) {
    const int obase = wv * 48 + m * 16 + g * 4;
    float bv0 = b1[obase], bv1 = b1[obase + 1], bv2 = b1[obase + 2], bv3 = b1[obase + 3];
#pragma unroll
    for (int n = 0; n < 4; ++n) {
      const size_t pcol = pbase + n * 16 + lid;
      h1[(size_t)(obase + 0) * (NB * HW) + pcol] = fmaxf(acc[m][n][0] + bv0, 0.f);
      h1[(size_t)(obase + 1) * (NB * HW) + pcol] = fmaxf(acc[m][n][1] + bv1, 0.f);
      h1[(size_t)(obase + 2) * (NB * HW) + pcol] = fmaxf(acc[m][n][2] + bv2, 0.f);
      h1[(size_t)(obase + 3) * (NB * HW) + pcol] = fmaxf(acc[m][n][3] + bv3, 0.f);
    }
  }
}

// ---------------------------------------------------------------------------
// Kernel 3: off head  off[p][j] = b2[j] + sum_c w2[j][c]*h1[c][p]
// ---------------------------------------------------------------------------
__global__ __launch_bounds__(256) void k_offhead(
    const float* __restrict__ h1, const float* __restrict__ w2,
    const float* __restrict__ b2, float* __restrict__ off) {
  __shared__ float w2l[18 * NC];
  const int tid = threadIdx.x;
  for (int i = tid; i < 18 * NC; i += 256) w2l[i] = w2[i];
  __syncthreads();
  const int px = tid & 127;
  const int jh = tid >> 7;
  const size_t p = (size_t)blockIdx.x * 128 + px;
  float acc[9];
#pragma unroll
  for (int jj = 0; jj < 9; ++jj) acc[jj] = b2[jh * 9 + jj];
  for (int c = 0; c < NC; ++c) {
    float v = h1[(size_t)c * (NB * HW) + p];
#pragma unroll
    for (int jj = 0; jj < 9; ++jj) acc[jj] += w2l[(jh * 9 + jj) * NC + c] * v;
  }
#pragma unroll
  for (int jj = 0; jj < 9; ++jj) off[p * 18 + jh * 9 + jj] = acc[jj];
}

// ---------------------------------------------------------------------------
// Kernel 4: deformable sampling + window attention (unchanged).
// ---------------------------------------------------------------------------
__global__ __launch_bounds__(256) void k_attn(
    const float* __restrict__ q, const float* __restrict__ k,
    const float* __restrict__ v, const float* __restrict__ off,
    float* __restrict__ pre) {
  __shared__ float slog[4][6][9];
  __shared__ float sattn[4][6][9];
  const int wv = threadIdx.x >> 6;
  const int lane = threadIdx.x & 63;
  const size_t p = (size_t)blockIdx.x * 4 + wv;
  const int b = (int)(p >> 14);
  const int pp = (int)(p & 16383);
  const int y = pp >> 7, x = pp & 127;
  const float* qrow = q + p * NC;
  float qv0 = qrow[lane], qv1 = qrow[lane + 64], qv2 = qrow[lane + 128];
  float vsr[9][3];
#pragma unroll
  for (int idx = 0; idx < 9; ++idx) {
    const int di = idx / 3 - 1, dj = idx % 3 - 1;
    const int yy = y + di, xx = x + dj;
    const bool inb = (yy >= 0) && (yy < 128) && (xx >= 0) && (xx < 128);
    float ks0 = 0.f, ks1 = 0.f, ks2 = 0.f;
    float v0 = 0.f, v1 = 0.f, v2 = 0.f;
    if (inb) {
      const size_t sp = (size_t)b * HW + yy * 128 + xx;
      const float sx = off[sp * 18 + idx * 2 + 0];
      const float sy = off[sp * 18 + idx * 2 + 1];
      const float fx0 = floorf(sx), fy0 = floorf(sy);
      const float wx = sx - fx0, wy = sy - fy0;
#pragma unroll
      for (int cyx = 0; cyx < 4; ++cyx) {
        const int cy = cyx >> 1, cx = cyx & 1;
        const float xi = fx0 + cx, yi = fy0 + cy;
        const float wgt = (cx ? wx : 1.f - wx) * (cy ? wy : 1.f - wy);
        const bool okc = (xi >= 0.f) && (xi <= 127.f) && (yi >= 0.f) && (yi <= 127.f);
        if (okc) {
          const int xc = (int)xi, yc = (int)yi;
          const size_t cb = ((size_t)b * HW + yc * 128 + xc) * NC + lane;
          ks0 += wgt * k[cb];       v0 += wgt * v[cb];
          ks1 += wgt * k[cb + 64];  v1 += wgt * v[cb + 64];
          ks2 += wgt * k[cb + 128]; v2 += wgt * v[cb + 128];
        }
      }
    }
    vsr[idx][0] = v0; vsr[idx][1] = v1; vsr[idx][2] = v2;
    float p0 = qv0 * ks0, p1 = qv1 * ks1, p2 = qv2 * ks2;
#pragma unroll
    for (int m = 16; m >= 1; m >>= 1) {
      p0 += __shfl_xor(p0, m);
      p1 += __shfl_xor(p1, m);
      p2 += __shfl_xor(p2, m);
    }
    if ((lane & 31) == 0) {
      const int hb = lane >> 5;
      slog[wv][hb + 0][idx] = p0;
      slog[wv][hb + 2][idx] = p1;
      slog[wv][hb + 4][idx] = p2;
    }
  }
  __syncthreads();
  if (lane < 6) {
    float mx = -1e30f;
#pragma unroll
    for (int i = 0; i < 9; ++i) mx = fmaxf(mx, slog[wv][lane][i]);
    float e[9];
    float s = 0.f;
#pragma unroll
    for (int i = 0; i < 9; ++i) { e[i] = expf(slog[wv][lane][i] - mx); s += e[i]; }
    const float inv = 1.f / s;
#pragma unroll
    for (int i = 0; i < 9; ++i) sattn[wv][lane][i] = e[i] * inv;
  }
  __syncthreads();
  float o0 = 0.f, o1 = 0.f, o2 = 0.f;
  const int hb = lane >> 5;
#pragma unroll
  for (int idx = 0; idx < 9; ++idx) {
    o0 += sattn[wv][hb + 0][idx] * vsr[idx][0];
    o1 += sattn[wv][hb + 2][idx] * vsr[idx][1];
    o2 += sattn[wv][hb + 4][idx] * vsr[idx][2];
  }
  float* prow = pre + p * NC;
  prow[lane] = o0;
  prow[lane + 64] = o1;
  prow[lane + 128] = o2;
}

// ---------------------------------------------------------------------------
// Kernel 5: proj (unchanged).
// ---------------------------------------------------------------------------
__device__ inline void fma4_proj(float4& a, const float4 w, const float4 x0,
                                 const float4 x1, const float4 x2, const float4 x3) {
  a.x += w.x * x0.x + w.y * x1.x + w.z * x2.x + w.w * x3.x;
  a.y += w.x * x0.y + w.y * x1.y + w.z * x2.y + w.w * x3.y;
  a.z += w.x * x0.z + w.y * x1.z + w.z * x2.z + w.w * x3.z;
  a.w += w.x * x0.w + w.y * x1.w + w.z * x2.w + w.w * x3.w;
}

__global__ __launch_bounds__(256) void k_proj(
    const float* __restrict__ pre, const float* __restrict__ wp,
    const float* __restrict__ bp, float* __restrict__ out) {
  __shared__ float xl[NC * 68];
  __shared__ float wl[64 * WPAD];
  const int tid = threadIdx.x;
  const int tile = blockIdx.x;
  const int b = tile >> 8;
  const int p0 = (tile & 255) << 6;
  const float* pb = pre + ((size_t)b * HW + p0) * NC;
  for (int i = tid; i < 64 * NC; i += 256) {
    int pix = i / NC, c = i - pix * NC;
    xl[c * 68 + pix] = pb[i];
  }
  const int oc0 = blockIdx.y << 6;
  for (int i = tid; i < 64 * NC; i += 256) {
    int o = i / NC, c = i - o * NC;
    wl[o * WPAD + c] = wp[(size_t)(oc0 + o) * NC + ((c & 31) * 6 + (c >> 5))];
  }
  __syncthreads();
  const int pg = tid & 15, og = tid >> 4;
  float bi0 = bp[oc0 + og * 4 + 0];
  float bi1 = bp[oc0 + og * 4 + 1];
  float bi2 = bp[oc0 + og * 4 + 2];
  float bi3 = bp[oc0 + og * 4 + 3];
  float4 a0 = make_float4(bi0, bi0, bi0, bi0);
  float4 a1 = make_float4(bi1, bi1, bi1, bi1);
  float4 a2 = make_float4(bi2, bi2, bi2, bi2);
  float4 a3 = make_float4(bi3, bi3, bi3, bi3);
  const float* wbase = &wl[(og * 4) * WPAD];
  const float* xbase = &xl[pg * 4];
  for (int c = 0; c < NC; c += 4) {
    float4 w0 = *(const float4*)(wbase + c);
    float4 w1 = *(const float4*)(wbase + WPAD + c);
    float4 w2 = *(const float4*)(wbase + 2 * WPAD + c);
    float4 w3 = *(const float4*)(wbase + 3 * WPAD + c);
    float4 x0 = *(const float4*)(xbase + (c + 0) * 68);
    float4 x1 = *(const float4*)(xbase + (c + 1) * 68);
    float4 x2 = *(const float4*)(xbase + (c + 2) * 68);
    float4 x3 = *(const float4*)(xbase + (c + 3) * 68);
    fma4_proj(a0, w0, x0, x1, x2, x3);
    fma4_proj(a1, w1, x0, x1, x2, x3);
    fma4_proj(a2, w2, x0, x1, x2, x3);
    fma4_proj(a3, w3, x0, x1, x2, x3);
  }
  float* ob = out + ((size_t)b * NC + oc0 + og * 4) * HW + p0 + pg * 4;
  *(float4*)(ob + 0 * (size_t)HW) = a0;
  *(float4*)(ob + 1 * (size_t)HW) = a1;
  *(float4*)(ob + 2 * (size_t)HW) = a2;
  *(float4*)(ob + 3 * (size_t)HW) = a3;
}

extern "C" void kernel_launch(void* const* d_in, const int* in_sizes, int n_in,
                              void* d_out, int out_size, void* d_ws, size_t ws_size,
                              hipStream_t stream) {
  const float* x_q    = (const float*)d_in[0];
  const float* x_kv   = (const float*)d_in[1];
  const float* w_q    = (const float*)d_in[2];
  const float* w_kv   = (const float*)d_in[3];
  const float* w_off1 = (const float*)d_in[4];
  const float* b_off1 = (const float*)d_in[5];
  const float* w_off2 = (const float*)d_in[6];
  const float* b_off2 = (const float*)d_in[7];
  const float* w_proj = (const float*)d_in[8];
  const float* b_proj = (const float*)d_in[9];
  float* out = (float*)d_out;
  float* ws = (float*)d_ws;

  const size_t NPB = (size_t)NB * HW * NC;
  float* qb   = ws;
  float* kb   = ws + NPB;
  float* vb   = ws + 2 * NPB;
  float* preb = ws + 3 * NPB;          // also aliases h1 (dead before attn)
  float* offb = ws + 4 * NPB;
  float* h1b  = preb;
  ushort* wpk = (ushort*)d_out;        // packed conv weights; proj overwrites later

  const float scale = 0.17677669529663687f;
  dim3 blk(256);
  k_wpack<<<dim3(2592), blk, 0, stream>>>(w_off1, wpk);
  k_gemm_qkv<<<dim3(512, 3), blk, 0, stream>>>(x_q, w_q, qb, qb, scale);
  k_gemm_qkv<<<dim3(512, 6), blk, 0, stream>>>(x_kv, w_kv, kb, vb, 1.0f);
  k_conv_mfma<<<dim3(512), blk, 0, stream>>>(x_q, x_kv, wpk, b_off1, h1b);
  k_offhead<<<dim3(NB * 128), blk, 0, stream>>>(h1b, w_off2, b_off2, offb);
  k_attn<<<dim3(8192), blk, 0, stream>>>(qb, kb, vb, offb, preb);
  k_proj<<<dim3(512, 3), blk, 0, stream>>>(preb, w_proj, b_proj, out);
}

// Round 3
// 227.061 us; speedup vs baseline: 10.1990x; 2.3870x over previous
//
#include <hip/hip_runtime.h>
#include <math.h>

#define HW 16384
#define NB 2
#define NC 192

typedef __attribute__((ext_vector_type(8))) short bh8;
typedef __attribute__((ext_vector_type(4))) float f32x4;

__device__ inline ushort f2bf(float f) {
  union { float f; unsigned int u; } x; x.f = f;
  unsigned int r = x.u + 0x7fffu + ((x.u >> 16) & 1u);
  return (ushort)(r >> 16);
}
__device__ inline float bf2f(ushort u) {
  union { unsigned int i; float f; } x; x.i = ((unsigned int)u) << 16;
  return x.f;
}

// ---------------------------------------------------------------------------
// Kernel 0a: pack conv weights -> wpack[s=108][o=192][kk=32] bf16 (in d_out)
// ---------------------------------------------------------------------------
__global__ void k_wpack(const float* __restrict__ w1, ushort* __restrict__ wpack) {
  int i = blockIdx.x * 256 + threadIdx.x;  // 663552
  int s = i / 6144;
  int rem = i - s * 6144;
  int o = rem >> 5, kk = rem & 31;
  int dy = s / 36, t2 = s - dy * 36;
  int icc = t2 / 3, dxi = t2 - icc * 3;
  int ic = icc * 32 + kk;
  wpack[i] = f2bf(w1[(size_t)o * 3456 + (size_t)ic * 9 + dy * 3 + dxi]);
}

// ---------------------------------------------------------------------------
// Kernel 0b: pack GEMM weights -> wg[768][192] bf16.
// rows 0-191: w_q rows head-permuted, x scale. 192-575: w_kv permuted (k then v).
// 576-767: w_proj with COLUMN perm.
// ---------------------------------------------------------------------------
__global__ void k_wgpack(const float* __restrict__ wq, const float* __restrict__ wkv,
                         const float* __restrict__ wp, float scale,
                         ushort* __restrict__ wg) {
  int i = blockIdx.x * 256 + threadIdx.x;  // 147456
  int r = i / NC, c = i - r * NC;
  float v;
  if (r < 192) {
    int orow = (r & 31) * 6 + (r >> 5);
    v = wq[(size_t)orow * NC + c] * scale;
  } else if (r < 576) {
    int rp = r - 192;
    int t = rp >= 192 ? 1 : 0;
    int cc = rp - t * 192;
    int orow = t * 192 + (cc & 31) * 6 + (cc >> 5);
    v = wkv[(size_t)orow * NC + c];
  } else {
    int rp = r - 576;
    v = wp[(size_t)rp * NC + ((c & 31) * 6 + (c >> 5))];
  }
  wg[i] = f2bf(v);
}

// ---------------------------------------------------------------------------
// Kernel 0c: x fp32 NCHW -> xp bf16 NHWC [flat_px][384] (y=0: ch 0-191 from x_q,
// y=1: ch 192-383 from x_kv). LDS transpose, coalesced in and out.
// ---------------------------------------------------------------------------
__global__ __launch_bounds__(256) void k_xpack(const float* __restrict__ xq,
                                               const float* __restrict__ xkv,
                                               ushort* __restrict__ xp) {
  __shared__ float t[NC][65];
  const int tid = threadIdx.x;
  const size_t r0 = (size_t)blockIdx.x * 64;
  const int b = (int)(r0 >> 14);
  const int px0 = (int)(r0 & 16383);
  const float* src = (blockIdx.y == 0 ? xq : xkv) + (size_t)b * NC * HW + px0;
#pragma unroll
  for (int it = 0; it < 12; ++it) {
    int i = it * 256 + tid;  // 3072
    int c = i >> 4, q4 = i & 15;
    float4 v = *(const float4*)(src + (size_t)c * HW + q4 * 4);
    t[c][q4 * 4 + 0] = v.x; t[c][q4 * 4 + 1] = v.y;
    t[c][q4 * 4 + 2] = v.z; t[c][q4 * 4 + 3] = v.w;
  }
  __syncthreads();
  ushort* dst = xp + r0 * 384 + blockIdx.y * 192;
#pragma unroll
  for (int it = 0; it < 6; ++it) {
    int i = it * 256 + tid;  // 1536
    int px = i / 24, ch = i - px * 24;
    ushort4 u0, u1;
    u0.x = f2bf(t[ch * 8 + 0][px]); u0.y = f2bf(t[ch * 8 + 1][px]);
    u0.z = f2bf(t[ch * 8 + 2][px]); u0.w = f2bf(t[ch * 8 + 3][px]);
    u1.x = f2bf(t[ch * 8 + 4][px]); u1.y = f2bf(t[ch * 8 + 5][px]);
    u1.z = f2bf(t[ch * 8 + 6][px]); u1.w = f2bf(t[ch * 8 + 7][px]);
    *(ushort4*)&dst[(size_t)px * 384 + ch * 8] = u0;
    *(ushort4*)&dst[(size_t)px * 384 + ch * 8 + 4] = u1;
  }
}

// ---------------------------------------------------------------------------
// MFMA GEMM engine: 64px x 64o tile, K=192 staged in LDS (swizzled chunks).
// ---------------------------------------------------------------------------
__device__ inline void stage64(ushort* lds, const ushort* src, int rowStride,
                               int tid) {
#pragma unroll
  for (int it = 0; it < 6; ++it) {
    int i = it * 256 + tid;  // 1536
    int row = i / 24, c = i - row * 24;
    int pos = (c & 24) | ((c & 7) ^ (row & 7));
    uint4 v = *(const uint4*)(src + (size_t)row * rowStride + c * 8);
    *(uint4*)&lds[row * NC + pos * 8] = v;
  }
}
__device__ inline bh8 frag64(const ushort* lds, int row, int c) {
  int pos = (c & 24) | ((c & 7) ^ (row & 7));
  return *(const bh8*)&lds[row * NC + pos * 8];
}

// out bf16 [px][192]; outA for o<192, outB for o>=192.
__global__ __launch_bounds__(256) void k_gemm_mfma(
    const ushort* __restrict__ xp, int cOff, const ushort* __restrict__ wg,
    ushort* __restrict__ outA, ushort* __restrict__ outB) {
  __shared__ __attribute__((aligned(16))) ushort xs[64 * NC];
  __shared__ __attribute__((aligned(16))) ushort ws2[64 * NC];
  const int tid = threadIdx.x;
  const size_t p0 = (size_t)blockIdx.x * 64;
  const int o0 = blockIdx.y * 64;
  stage64(xs, xp + p0 * 384 + cOff, 384, tid);
  stage64(ws2, wg + (size_t)o0 * NC, NC, tid);
  __syncthreads();
  const int lid = tid & 15, g = (tid >> 4) & 3, wv = tid >> 6;
  const int wo = (wv & 1) * 32, wp = (wv >> 1) * 32;
  f32x4 acc[2][2];
#pragma unroll
  for (int m = 0; m < 2; ++m)
#pragma unroll
    for (int n = 0; n < 2; ++n) acc[m][n] = (f32x4){0.f, 0.f, 0.f, 0.f};
#pragma unroll
  for (int k = 0; k < 6; ++k) {
    bh8 a0 = frag64(ws2, wo + lid, k * 4 + g);
    bh8 a1 = frag64(ws2, wo + 16 + lid, k * 4 + g);
    bh8 b0 = frag64(xs, wp + lid, k * 4 + g);
    bh8 b1 = frag64(xs, wp + 16 + lid, k * 4 + g);
    acc[0][0] = __builtin_amdgcn_mfma_f32_16x16x32_bf16(a0, b0, acc[0][0], 0, 0, 0);
    acc[0][1] = __builtin_amdgcn_mfma_f32_16x16x32_bf16(a0, b1, acc[0][1], 0, 0, 0);
    acc[1][0] = __builtin_amdgcn_mfma_f32_16x16x32_bf16(a1, b0, acc[1][0], 0, 0, 0);
    acc[1][1] = __builtin_amdgcn_mfma_f32_16x16x32_bf16(a1, b1, acc[1][1], 0, 0, 0);
  }
  const int t = o0 >= 192 ? 1 : 0;
  ushort* dst = t ? outB : outA;
  const int od = o0 - t * 192;
#pragma unroll
  for (int m = 0; m < 2; ++m)
#pragma unroll
    for (int n = 0; n < 2; ++n) {
      int orow = od + wo + m * 16 + g * 4;
      size_t px = p0 + wp + n * 16 + lid;
      ushort4 u;
      u.x = f2bf(acc[m][n][0]); u.y = f2bf(acc[m][n][1]);
      u.z = f2bf(acc[m][n][2]); u.w = f2bf(acc[m][n][3]);
      *(ushort4*)&dst[px * NC + orow] = u;
    }
}

// proj: B = pre bf16 [px][192], out fp32 NCHW + bias.
__global__ __launch_bounds__(256) void k_proj_mfma(
    const ushort* __restrict__ pre, const ushort* __restrict__ wg,
    const float* __restrict__ bp, float* __restrict__ out) {
  __shared__ __attribute__((aligned(16))) ushort xs[64 * NC];
  __shared__ __attribute__((aligned(16))) ushort ws2[64 * NC];
  const int tid = threadIdx.x;
  const size_t p0 = (size_t)blockIdx.x * 64;
  const int o0 = blockIdx.y * 64;
  stage64(xs, pre + p0 * NC, NC, tid);
  stage64(ws2, wg + (size_t)o0 * NC, NC, tid);
  __syncthreads();
  const int lid = tid & 15, g = (tid >> 4) & 3, wv = tid >> 6;
  const int wo = (wv & 1) * 32, wp = (wv >> 1) * 32;
  f32x4 acc[2][2];
#pragma unroll
  for (int m = 0; m < 2; ++m)
#pragma unroll
    for (int n = 0; n < 2; ++n) acc[m][n] = (f32x4){0.f, 0.f, 0.f, 0.f};
#pragma unroll
  for (int k = 0; k < 6; ++k) {
    bh8 a0 = frag64(ws2, wo + lid, k * 4 + g);
    bh8 a1 = frag64(ws2, wo + 16 + lid, k * 4 + g);
    bh8 b0 = frag64(xs, wp + lid, k * 4 + g);
    bh8 b1 = frag64(xs, wp + 16 + lid, k * 4 + g);
    acc[0][0] = __builtin_amdgcn_mfma_f32_16x16x32_bf16(a0, b0, acc[0][0], 0, 0, 0);
    acc[0][1] = __builtin_amdgcn_mfma_f32_16x16x32_bf16(a0, b1, acc[0][1], 0, 0, 0);
    acc[1][0] = __builtin_amdgcn_mfma_f32_16x16x32_bf16(a1, b0, acc[1][0], 0, 0, 0);
    acc[1][1] = __builtin_amdgcn_mfma_f32_16x16x32_bf16(a1, b1, acc[1][1], 0, 0, 0);
  }
#pragma unroll
  for (int m = 0; m < 2; ++m)
#pragma unroll
    for (int n = 0; n < 2; ++n) {
      int oc = o0 + wo + m * 16 + g * 4;
      size_t pxf = p0 + wp + n * 16 + lid;
      int b = (int)(pxf >> 14);
      int px = (int)(pxf & 16383);
#pragma unroll
      for (int j = 0; j < 4; ++j)
        out[((size_t)b * NC + oc + j) * HW + px] = acc[m][n][j] + bp[oc + j];
    }
}

// ---------------------------------------------------------------------------
// conv3x3(384->192) via bf16 MFMA implicit im2col (unchanged from R2).
// ---------------------------------------------------------------------------
__global__ __launch_bounds__(256, 2) void k_conv_mfma(
    const float* __restrict__ xq, const float* __restrict__ xkv,
    const ushort* __restrict__ wpack, const float* __restrict__ b1,
    float* __restrict__ h1) {
  __shared__ __attribute__((aligned(16))) char smem[41472];
  const int tid = threadIdx.x;
  const int bi = blockIdx.x;
  const int b = bi >> 8;
  const int y = (bi >> 1) & 127;
  const int x0 = (bi & 1) << 6;
  const int lid = tid & 15;
  const int g = (tid >> 4) & 3;
  const int wv = tid >> 6;
  f32x4 acc[3][4];
#pragma unroll
  for (int m = 0; m < 3; ++m)
#pragma unroll
    for (int n = 0; n < 4; ++n) acc[m][n] = (f32x4){0.f, 0.f, 0.f, 0.f};
  const size_t xb = (size_t)b * NC * HW;

  for (int dy = 0; dy < 3; ++dy) {
    const int yy = y + dy - 1;
    const bool yok = (yy >= 0) && (yy < 128);
    for (int icc = 0; icc < 12; ++icc) {
      __syncthreads();
#pragma unroll
      for (int it = 0; it < 3; ++it) {
        int i = tid + (it << 8);
        if (i < 576) {
          int g4 = i >> 5, kk = i & 31;
          int xg = x0 - 4 + (g4 << 2);
          int c = icc * 32 + kk;
          float4 v = make_float4(0.f, 0.f, 0.f, 0.f);
          if (yok && xg >= 0 && xg <= 124) {
            const float* src = (c < NC) ? (xq + xb + (size_t)c * HW)
                                        : (xkv + xb + (size_t)(c - NC) * HW);
            v = *(const float4*)(src + yy * 128 + xg);
          }
          ushort bfv[4] = {f2bf(v.x), f2bf(v.y), f2bf(v.z), f2bf(v.w)};
          int q = kk >> 3, klo = (kk & 7) << 1;
#pragma unroll
          for (int e = 0; e < 4; ++e) {
            int slot = (g4 << 2) + e;
            *(ushort*)(smem + 36864 + slot * 64 +
                       (((q ^ (slot >> 1)) & 3) << 4) + klo) = bfv[e];
          }
        }
      }
      const int s0 = (dy * 12 + icc) * 3;
#pragma unroll
      for (int it = 0; it < 9; ++it) {
        int i = tid + (it << 8);
        int dxi = i / 768;
        int rem = i - dxi * 768;
        int o = rem >> 2, q = rem & 3;
        uint4 wq = *(const uint4*)(wpack + (size_t)(s0 + dxi) * 6144 + rem * 8);
        *(uint4*)(smem + dxi * 12288 + o * 64 + (((q ^ (o >> 1)) & 3) << 4)) = wq;
      }
      __syncthreads();
#pragma unroll
      for (int dxi = 0; dxi < 3; ++dxi) {
        bh8 af[3], bfr[4];
#pragma unroll
        for (int m = 0; m < 3; ++m) {
          int o = wv * 48 + m * 16 + lid;
          af[m] = *(const bh8*)(smem + dxi * 12288 + o * 64 +
                                (((g ^ (o >> 1)) & 3) << 4));
        }
#pragma unroll
        for (int n = 0; n < 4; ++n) {
          int slot = n * 16 + lid + 3 + dxi;
          bfr[n] = *(const bh8*)(smem + 36864 + slot * 64 +
                                 (((g ^ (slot >> 1)) & 3) << 4));
        }
#pragma unroll
        for (int m = 0; m < 3; ++m)
#pragma unroll
          for (int n = 0; n < 4; ++n)
            acc[m][n] = __builtin_amdgcn_mfma_f32_16x16x32_bf16(
                af[m], bfr[n], acc[m][n], 0, 0, 0);
      }
    }
  }
  const size_t pbase = (size_t)b * HW + y * 128 + x0;
#pragma unroll
  for (int m = 0; m < 3; ++m) {
    const int obase = wv * 48 + m * 16 + g * 4;
    float bv0 = b1[obase], bv1 = b1[obase + 1], bv2 = b1[obase + 2], bv3 = b1[obase + 3];
#pragma unroll
    for (int n = 0; n < 4; ++n) {
      const size_t pcol = pbase + n * 16 + lid;
      h1[(size_t)(obase + 0) * (NB * HW) + pcol] = fmaxf(acc[m][n][0] + bv0, 0.f);
      h1[(size_t)(obase + 1) * (NB * HW) + pcol] = fmaxf(acc[m][n][1] + bv1, 0.f);
      h1[(size_t)(obase + 2) * (NB * HW) + pcol] = fmaxf(acc[m][n][2] + bv2, 0.f);
      h1[(size_t)(obase + 3) * (NB * HW) + pcol] = fmaxf(acc[m][n][3] + bv3, 0.f);
    }
  }
}

// ---------------------------------------------------------------------------
// off head
// ---------------------------------------------------------------------------
__global__ __launch_bounds__(256) void k_offhead(
    const float* __restrict__ h1, const float* __restrict__ w2,
    const float* __restrict__ b2, float* __restrict__ off) {
  __shared__ float w2l[18 * NC];
  const int tid = threadIdx.x;
  for (int i = tid; i < 18 * NC; i += 256) w2l[i] = w2[i];
  __syncthreads();
  const int px = tid & 127;
  const int jh = tid >> 7;
  const size_t p = (size_t)blockIdx.x * 128 + px;
  float acc[9];
#pragma unroll
  for (int jj = 0; jj < 9; ++jj) acc[jj] = b2[jh * 9 + jj];
  for (int c = 0; c < NC; ++c) {
    float v = h1[(size_t)c * (NB * HW) + p];
#pragma unroll
    for (int jj = 0; jj < 9; ++jj) acc[jj] += w2l[(jh * 9 + jj) * NC + c] * v;
  }
#pragma unroll
  for (int jj = 0; jj < 9; ++jj) off[p * 18 + jh * 9 + jj] = acc[jj];
}

// ---------------------------------------------------------------------------
// sampling + window attention; q/k/v bf16 in, pre bf16 out, fp32 math.
// ---------------------------------------------------------------------------
__global__ __launch_bounds__(256) void k_attn(
    const ushort* __restrict__ q, const ushort* __restrict__ k,
    const ushort* __restrict__ v, const float* __restrict__ off,
    ushort* __restrict__ pre) {
  __shared__ float slog[4][6][9];
  __shared__ float sattn[4][6][9];
  const int wv = threadIdx.x >> 6;
  const int lane = threadIdx.x & 63;
  const size_t p = (size_t)blockIdx.x * 4 + wv;
  const int b = (int)(p >> 14);
  const int pp = (int)(p & 16383);
  const int y = pp >> 7, x = pp & 127;
  const ushort* qrow = q + p * NC;
  float qv0 = bf2f(qrow[lane]), qv1 = bf2f(qrow[lane + 64]), qv2 = bf2f(qrow[lane + 128]);
  float vsr[9][3];
#pragma unroll
  for (int idx = 0; idx < 9; ++idx) {
    const int di = idx / 3 - 1, dj = idx % 3 - 1;
    const int yy = y + di, xx = x + dj;
    const bool inb = (yy >= 0) && (yy < 128) && (xx >= 0) && (xx < 128);
    float ks0 = 0.f, ks1 = 0.f, ks2 = 0.f;
    float v0 = 0.f, v1 = 0.f, v2 = 0.f;
    if (inb) {
      const size_t sp = (size_t)b * HW + yy * 128 + xx;
      const float sx = off[sp * 18 + idx * 2 + 0];
      const float sy = off[sp * 18 + idx * 2 + 1];
      const float fx0 = floorf(sx), fy0 = floorf(sy);
      const float wx = sx - fx0, wy = sy - fy0;
#pragma unroll
      for (int cyx = 0; cyx < 4; ++cyx) {
        const int cy = cyx >> 1, cx = cyx & 1;
        const float xi = fx0 + cx, yi = fy0 + cy;
        const float wgt = (cx ? wx : 1.f - wx) * (cy ? wy : 1.f - wy);
        const bool okc = (xi >= 0.f) && (xi <= 127.f) && (yi >= 0.f) && (yi <= 127.f);
        if (okc) {
          const int xc = (int)xi, yc = (int)yi;
          const size_t cb = ((size_t)b * HW + yc * 128 + xc) * NC + lane;
          ks0 += wgt * bf2f(k[cb]);       v0 += wgt * bf2f(v[cb]);
          ks1 += wgt * bf2f(k[cb + 64]);  v1 += wgt * bf2f(v[cb + 64]);
          ks2 += wgt * bf2f(k[cb + 128]); v2 += wgt * bf2f(v[cb + 128]);
        }
      }
    }
    vsr[idx][0] = v0; vsr[idx][1] = v1; vsr[idx][2] = v2;
    float p0 = qv0 * ks0, p1 = qv1 * ks1, p2 = qv2 * ks2;
#pragma unroll
    for (int m = 16; m >= 1; m >>= 1) {
      p0 += __shfl_xor(p0, m);
      p1 += __shfl_xor(p1, m);
      p2 += __shfl_xor(p2, m);
    }
    if ((lane & 31) == 0) {
      const int hb = lane >> 5;
      slog[wv][hb + 0][idx] = p0;
      slog[wv][hb + 2][idx] = p1;
      slog[wv][hb + 4][idx] = p2;
    }
  }
  __syncthreads();
  if (lane < 6) {
    float mx = -1e30f;
#pragma unroll
    for (int i = 0; i < 9; ++i) mx = fmaxf(mx, slog[wv][lane][i]);
    float e[9];
    float s = 0.f;
#pragma unroll
    for (int i = 0; i < 9; ++i) { e[i] = expf(slog[wv][lane][i] - mx); s += e[i]; }
    const float inv = 1.f / s;
#pragma unroll
    for (int i = 0; i < 9; ++i) sattn[wv][lane][i] = e[i] * inv;
  }
  __syncthreads();
  float o0 = 0.f, o1 = 0.f, o2 = 0.f;
  const int hb = lane >> 5;
#pragma unroll
  for (int idx = 0; idx < 9; ++idx) {
    o0 += sattn[wv][hb + 0][idx] * vsr[idx][0];
    o1 += sattn[wv][hb + 2][idx] * vsr[idx][1];
    o2 += sattn[wv][hb + 4][idx] * vsr[idx][2];
  }
  ushort* prow = pre + p * NC;
  prow[lane] = f2bf(o0);
  prow[lane + 64] = f2bf(o1);
  prow[lane + 128] = f2bf(o2);
}

extern "C" void kernel_launch(void* const* d_in, const int* in_sizes, int n_in,
                              void* d_out, int out_size, void* d_ws, size_t ws_size,
                              hipStream_t stream) {
  const float* x_q    = (const float*)d_in[0];
  const float* x_kv   = (const float*)d_in[1];
  const float* w_q    = (const float*)d_in[2];
  const float* w_kv   = (const float*)d_in[3];
  const float* w_off1 = (const float*)d_in[4];
  const float* b_off1 = (const float*)d_in[5];
  const float* w_off2 = (const float*)d_in[6];
  const float* b_off2 = (const float*)d_in[7];
  const float* w_proj = (const float*)d_in[8];
  const float* b_proj = (const float*)d_in[9];
  float* out = (float*)d_out;

  char* W = (char*)d_ws;
  const size_t SB = (size_t)NB * HW * NC * 2;  // 12,582,912 B (bf16 field)
  ushort* qb   = (ushort*)W;
  ushort* kb   = (ushort*)(W + SB);
  ushort* vb   = (ushort*)(W + 2 * SB);
  ushort* preb = (ushort*)(W + 3 * SB);
  float*  offb = (float*)(W + 4 * SB);                    // 2,359,296 B
  ushort* wg   = (ushort*)(W + 4 * SB + 2359296);         //   294,912 B
  float*  h1b  = (float*)(W + 4 * SB + 2359296 + 294912); // 25,165,824 B (union)
  ushort* xp   = (ushort*)h1b;                            // xp dead before conv
  ushort* wpk  = (ushort*)d_out;  // conv weights; proj overwrites later

  const float scale = 0.17677669529663687f;
  dim3 blk(256);
  k_wpack<<<dim3(2592), blk, 0, stream>>>(w_off1, wpk);
  k_wgpack<<<dim3(576), blk, 0, stream>>>(w_q, w_kv, w_proj, scale, wg);
  k_xpack<<<dim3(512, 2), blk, 0, stream>>>(x_q, x_kv, xp);
  k_gemm_mfma<<<dim3(512, 3), blk, 0, stream>>>(xp, 0, wg, qb, qb);
  k_gemm_mfma<<<dim3(512, 6), blk, 0, stream>>>(xp, 192, wg + 192 * NC, kb, vb);
  k_conv_mfma<<<dim3(512), blk, 0, stream>>>(x_q, x_kv, wpk, b_off1, h1b);
  k_offhead<<<dim3(NB * 128), blk, 0, stream>>>(h1b, w_off2, b_off2, offb);
  k_attn<<<dim3(8192), blk, 0, stream>>>(qb, kb, vb, offb, preb);
  k_proj_mfma<<<dim3(512, 3), blk, 0, stream>>>(preb, wg + 576 * NC, b_proj, out);
}